// Round 3
// 1945.090 us; speedup vs baseline: 1.2772x; 1.2772x over previous
//
#include <hip/hip_runtime.h>

#define HW 16384
typedef unsigned int uint32;
typedef unsigned short ushort;
typedef __attribute__((ext_vector_type(8))) short short8;
typedef __attribute__((ext_vector_type(4))) float floatx4;
typedef __attribute__((ext_vector_type(4))) unsigned int uint32x4;

__device__ __forceinline__ float bf2f(ushort u) {
    union { uint32 i; float f; } x; x.i = ((uint32)u) << 16; return x.f;
}
__device__ __forceinline__ ushort f2bf(float f) {
    union { float f; uint32 i; } x; x.f = f;
    uint32 r = x.i + 0x7fffu + ((x.i >> 16) & 1u);
    return (ushort)(r >> 16);
}

// ---- dtype detector: fp32 data read as bf16 halves has wild exponents ----
__global__ __launch_bounds__(256) void detect_dtype(const ushort* __restrict__ x,
                                                    int* __restrict__ flag) {
    __shared__ int cnt;
    if (threadIdx.x == 0) cnt = 0;
    __syncthreads();
    int c = 0;
    for (int i = threadIdx.x; i < 8192; i += 256) {
        int e = (x[i] >> 7) & 0xFF;
        if (e >= 200) c++;
    }
    atomicAdd(&cnt, c);
    __syncthreads();
    if (threadIdx.x == 0) *flag = (cnt > 100) ? 1 : 0;  // 1 => inputs are fp32
}

// ---- weight convert: wqkv -> bf16 [576][192]; dw,wproj,temp -> fp32 ----
__global__ __launch_bounds__(256) void convert_weights(
    const void* __restrict__ wqkv, const void* __restrict__ dw0,
    const void* __restrict__ dw1, const void* __restrict__ dw2,
    const void* __restrict__ wproj, const void* __restrict__ temp,
    const int* __restrict__ flag,
    ushort* __restrict__ wbf, float* __restrict__ dwf,
    float* __restrict__ wprojf, float* __restrict__ tempf) {
    int fl = *flag;
    int idx = blockIdx.x * 256 + threadIdx.x;
#define RD(p, k) (fl ? ((const float*)(p))[k] : bf2f(((const ushort*)(p))[k]))
    if (idx < 110592) {           // w_qkv [576][192] row-major bf16 (k-contiguous)
        wbf[idx] = f2bf(RD(wqkv, idx));
        return;
    }
    idx -= 110592;
    if (idx < 15552) {            // 3 x [576*9]
        const void* p = (idx < 5184) ? dw0 : ((idx < 10368) ? dw1 : dw2);
        dwf[idx] = RD(p, idx % 5184);
        return;
    }
    idx -= 15552;
    if (idx < 110592) {           // w_proj [192][576] row-major fp32
        wprojf[idx] = RD(wproj, idx);
        return;
    }
    idx -= 110592;
    if (idx < 8) tempf[idx] = RD(temp, idx);
#undef RD
}

// ---- qkv = W @ x via MFMA 16x16x32 bf16. Block: 128 n, all 576 o. ----
// Staging vectorized: uint32x4 loads + bit-exact repack (bf16: f2bf(bf2f(u))==u).
__global__ __launch_bounds__(256, 3) void qkv_mfma(const void* __restrict__ xv,
    const ushort* __restrict__ wbf, const int* __restrict__ flag,
    ushort* __restrict__ qkv) {
    int fl = *flag;
    int blk = blockIdx.x;
    int b = blk >> 7; int n0 = (blk & 127) << 7;
    int t = threadIdx.x;
    __shared__ uint32 fb[12672];  // 6 k-steps * 8 n-subtiles * 264 (256 + 8 pad)
    size_t xbase = (size_t)b * 192 * HW + n0;
    for (int k = 0; k < 6; ++k) {
        int seg = t + k * 256;        // 1536 segs: (c-pair, 8 consecutive n)
        int c2 = seg >> 4;            // 0..95
        int n8 = (seg & 15) << 3;     // 0,8,...,120
        int c = c2 * 2;
        uint32 pk[8];
        if (fl) {
            const float* xp = (const float*)xv + xbase;
            const floatx4* p0 = (const floatx4*)(xp + (size_t)c * HW + n8);
            const floatx4* p1 = (const floatx4*)(xp + (size_t)(c + 1) * HW + n8);
            floatx4 f0a = p0[0], f0b = p0[1];
            floatx4 f1a = p1[0], f1b = p1[1];
#pragma unroll
            for (int i = 0; i < 4; ++i) {
                pk[i]     = (uint32)f2bf(f0a[i]) | ((uint32)f2bf(f1a[i]) << 16);
                pk[i + 4] = (uint32)f2bf(f0b[i]) | ((uint32)f2bf(f1b[i]) << 16);
            }
        } else {
            const ushort* xp = (const ushort*)xv + xbase;
            uint32x4 u0 = *(const uint32x4*)(xp + (size_t)c * HW + n8);
            uint32x4 u1 = *(const uint32x4*)(xp + (size_t)(c + 1) * HW + n8);
#pragma unroll
            for (int wq = 0; wq < 4; ++wq) {
                pk[2 * wq]     = (u0[wq] & 0xffffu) | (u1[wq] << 16);
                pk[2 * wq + 1] = (u0[wq] >> 16) | (u1[wq] & 0xffff0000u);
            }
        }
        int s = c >> 5, q = (c >> 3) & 3, j2 = c2 & 3;
        int nt = n8 >> 4, rb = n8 & 15;
        uint32* dst = fb + (s * 8 + nt) * 264 + (q * 16 + rb) * 4 + j2;
#pragma unroll
        for (int i = 0; i < 8; ++i) dst[i * 4] = pk[i];
    }
    __syncthreads();
    int w = t >> 6, lane = t & 63, q = lane >> 4, rr = lane & 15;
    for (int oc = 0; oc < 9; ++oc) {
        int o0 = oc * 64 + w * 16;
        const ushort* arow = wbf + (size_t)(o0 + rr) * 192;
        floatx4 acc[8];
#pragma unroll
        for (int nt = 0; nt < 8; ++nt) acc[nt] = (floatx4){0.f, 0.f, 0.f, 0.f};
        for (int s = 0; s < 6; ++s) {
            short8 af = *(const short8*)(arow + 32 * s + 8 * q);
            const uint32* bb = fb + s * 8 * 264 + (q * 16 + rr) * 4;
#pragma unroll
            for (int nt = 0; nt < 8; ++nt) {
                short8 bfr = *(const short8*)(bb + nt * 264);
                acc[nt] = __builtin_amdgcn_mfma_f32_16x16x32_bf16(af, bfr, acc[nt], 0, 0, 0);
            }
        }
        // C layout: row(=o) = q*4+reg, col(=n) = rr  [m89/m91 verified]
        ushort* drow = qkv + ((size_t)(b * 576 + o0 + q * 4)) * HW + n0 + rr;
#pragma unroll
        for (int nt = 0; nt < 8; ++nt)
#pragma unroll
            for (int reg = 0; reg < 4; ++reg)
                drow[(size_t)reg * HW + nt * 16] = f2bf(acc[nt][reg]);
    }
}

// ---- fused dwconv(q,k) + gram partials; block = (rowgroup, head, batch) ----
// Conv inputs staged global->LDS via short8 (bit copy); conv loop = r0 verbatim.
template<int D>
__global__ __launch_bounds__(256) void gram_fused(const ushort* __restrict__ qkv,
    const float* __restrict__ dwf, float* __restrict__ gpart, int br) {
    int rg = blockIdx.x, hd = blockIdx.y, b = blockIdx.z;
    int t = threadIdx.x;
    __shared__ ushort cs[48 * 132];    // conv outputs, row stride 132
    __shared__ ushort vin[48 * 384];   // staged inputs [cl][ky][128]
    float acc[3] = {0.f, 0.f, 0.f};
    for (int yi = 0; yi < 8; ++yi) {
        int y = rg * 8 + yi;
        __syncthreads();   // protect vin (prior conv reads) and cs (prior dot reads)
        // stage: 48 ch x 3 rows x 16 seg8 = 2304 segs, 9 per thread
        for (int it = 0; it < 9; ++it) {
            int seg = t + it * 256;
            int cl = seg / 48;
            int rem = seg - cl * 48;
            int kyr = rem >> 4;
            int px = (rem & 15) << 3;
            int yy = y + D * (kyr - 1);
            if ((unsigned)yy < 128u) {
                int cg = (cl < 24) ? (hd * 24 + cl) : (192 + hd * 24 + (cl - 24));
                const ushort* src = qkv + ((size_t)(b * 576 + cg)) * HW + (size_t)yy * 128 + px;
                *(short8*)(vin + (cl * 3 + kyr) * 128 + px) = *(const short8*)src;
            }
        }
        __syncthreads();
        // conv compute (r0 semantics, LDS source): 6144 outputs, 24 per thread
        for (int it = 0; it < 24; ++it) {
            int e = t + it * 256;
            int cl = e >> 7, xx = e & 127;
            int cg = (cl < 24) ? (hd * 24 + cl) : (192 + hd * 24 + (cl - 24));
            const ushort* vrow = vin + cl * 384;
            const float* w = dwf + (br * 576 + cg) * 9;
            float a = 0.f;
#pragma unroll
            for (int ky = 0; ky < 3; ++ky) {
                int yy = y + D * (ky - 1);
                if ((unsigned)yy < 128u) {
#pragma unroll
                    for (int kx = 0; kx < 3; ++kx) {
                        int x2 = xx + D * (kx - 1);
                        if ((unsigned)x2 < 128u)
                            a = fmaf(bf2f(vrow[ky * 128 + x2]), w[ky * 3 + kx], a);
                    }
                }
            }
            cs[cl * 132 + xx] = f2bf(a);
        }
        __syncthreads();
        const uint32* cs32 = (const uint32*)cs;
#pragma unroll
        for (int pi = 0; pi < 3; ++pi) {
            int p = t + pi * 256;
            if (p >= 624) break;
            int i, j;
            if (p < 576)      { i = p / 24;         j = 24 + p % 24; }
            else if (p < 600) { i = p - 576;        j = i; }
            else              { i = 24 + (p - 600); j = i; }
            const uint32* ra = cs32 + i * 66;
            const uint32* rb = cs32 + j * 66;
            float s = acc[pi];
            for (int xi = 0; xi < 64; ++xi) {
                uint32 ua = ra[xi], ub = rb[xi];
                s = fmaf(bf2f((ushort)(ua & 0xffff)), bf2f((ushort)(ub & 0xffff)), s);
                s = fmaf(bf2f((ushort)(ua >> 16)), bf2f((ushort)(ub >> 16)), s);
            }
            acc[pi] = s;
        }
    }
    float* gp = gpart + ((size_t)((b * 8 + hd) * 16 + rg)) * 624;
#pragma unroll
    for (int pi = 0; pi < 3; ++pi) {
        int p = t + pi * 256;
        if (p < 624) gp[p] = acc[pi];
    }
}

// ---- reduce gram, softmax, fold with w_proj -> Pbf[br][o][c] bf16 ----
__global__ __launch_bounds__(256) void attn_p(const float* __restrict__ gpart,
    const float* __restrict__ wprojf, const float* __restrict__ tempf,
    ushort* __restrict__ Pbf, int br) {
    int otile = blockIdx.x; int b_ = blockIdx.y;
    int t = threadIdx.x;
    __shared__ float G[8][624];
    __shared__ float A[8][24][24];
    for (int e = t; e < 8 * 624; e += 256) {
        int hd = e / 624, idx = e % 624;
        const float* gp = gpart + ((size_t)((b_ * 8 + hd) * 16)) * 624 + idx;
        float s = 0.f;
#pragma unroll
        for (int rgi = 0; rgi < 16; ++rgi) s += gp[(size_t)rgi * 624];
        G[hd][idx] = s;
    }
    __syncthreads();
    if (t < 192) {
        int hd = t / 24, i = t % 24;
        const float* g = G[hd];
        float dq = fmaxf(sqrtf(fmaxf(g[576 + i], 0.f)), 1e-12f);
        float tv = tempf[hd];
        float lg[24]; float mx = -1e30f;
#pragma unroll
        for (int j = 0; j < 24; ++j) {
            float kn = fmaxf(sqrtf(fmaxf(g[600 + j], 0.f)), 1e-12f);
            lg[j] = g[i * 24 + j] / (dq * kn) * tv;
            mx = fmaxf(mx, lg[j]);
        }
        float sum = 0.f;
#pragma unroll
        for (int j = 0; j < 24; ++j) { lg[j] = __expf(lg[j] - mx); sum += lg[j]; }
        float inv = 1.f / sum;
#pragma unroll
        for (int j = 0; j < 24; ++j) A[hd][i][j] = lg[j] * inv;
    }
    __syncthreads();
    for (int e = t; e < 24 * 192; e += 256) {
        int o = otile * 24 + (e % 24);
        int c = e / 24;
        int hd = c / 24, dd = c % 24;
        const float* wr = wprojf + o * 576 + br * 192 + hd * 24;
        float s = 0.f;
#pragma unroll
        for (int i = 0; i < 24; ++i) s = fmaf(wr[i], A[hd][i][dd], s);
        Pbf[((size_t)(b_ * 3 + br) * 192 + o) * 192 + c] = f2bf(s);
    }
}

// ---- fused conv(v) + MFMA proj; conv inputs staged through LDS in 16-ch chunks ----
template<int D>
__device__ __forceinline__ void proj_branch(int br, int y, int b, int t,
    const ushort* __restrict__ qkv, const float* __restrict__ dwf,
    const ushort* __restrict__ Pbf, uint32* fb, ushort* vin, floatx4 (&acc)[3][8]) {
    ushort* fbs = (ushort*)fb;
    const ushort* qv = qkv + ((size_t)(b * 576 + 384)) * HW;
    const float* dwb = dwf + (br * 576 + 384) * 9;
    for (int cc = 0; cc < 12; ++cc) {   // 12 chunks x 16 channels
        __syncthreads();                // protects vin reuse and fb (prior MFMA reads)
        // stage: 16 ch x 3 rows x 16 seg8 = 768 segs, 3 per thread
        for (int k = 0; k < 3; ++k) {
            int seg = t + k * 256;
            int chl = seg / 48;
            int rem = seg - chl * 48;
            int kyr = rem >> 4;
            int px = (rem & 15) << 3;
            int yy = y + D * (kyr - 1);
            if ((unsigned)yy < 128u) {
                int c = cc * 16 + chl;
                const ushort* src = qv + (size_t)c * HW + (size_t)yy * 128 + px;
                *(short8*)(vin + (chl * 3 + kyr) * 128 + px) = *(const short8*)src;
            }
        }
        __syncthreads();
        // conv compute (r0 semantics, LDS source): 2048 outputs, 8 per thread
        for (int k = 0; k < 8; ++k) {
            int e = t + k * 256;
            int chl = e >> 7, xx = e & 127;
            int c = cc * 16 + chl;
            const ushort* vrow = vin + chl * 384;
            const float* wv = dwb + c * 9;
            float a = 0.f;
#pragma unroll
            for (int ky = 0; ky < 3; ++ky) {
                int yy = y + D * (ky - 1);
                if ((unsigned)yy < 128u) {
#pragma unroll
                    for (int kx = 0; kx < 3; ++kx) {
                        int x2 = xx + D * (kx - 1);
                        if ((unsigned)x2 < 128u)
                            a = fmaf(bf2f(vrow[ky * 128 + x2]), wv[ky * 3 + kx], a);
                    }
                }
            }
            int s = c >> 5, qq = (c >> 3) & 3, j = c & 7;
            int nt = xx >> 4, r = xx & 15;
            fbs[((s * 8 + nt) * 264 + (qq * 16 + r) * 4) * 2 + j] = f2bf(a);
        }
    }
    __syncthreads();
    int w = t >> 6, lane = t & 63, q = lane >> 4, rr = lane & 15;
    const ushort* Pb = Pbf + ((size_t)(b * 3 + br) * 192) * 192;
    for (int s = 0; s < 6; ++s) {
        short8 bfr[8];
        const uint32* bb = fb + s * 8 * 264 + (q * 16 + rr) * 4;
#pragma unroll
        for (int nt = 0; nt < 8; ++nt) bfr[nt] = *(const short8*)(bb + nt * 264);
#pragma unroll
        for (int ot = 0; ot < 3; ++ot) {
            int o0 = (w * 3 + ot) * 16;
            short8 af = *(const short8*)(Pb + (size_t)(o0 + rr) * 192 + 32 * s + 8 * q);
#pragma unroll
            for (int nt = 0; nt < 8; ++nt)
                acc[ot][nt] = __builtin_amdgcn_mfma_f32_16x16x32_bf16(af, bfr[nt], acc[ot][nt], 0, 0, 0);
        }
    }
}

__global__ __launch_bounds__(256, 2) void proj_mfma(const ushort* __restrict__ qkv,
    const float* __restrict__ dwf, const ushort* __restrict__ Pbf,
    const int* __restrict__ flag, void* __restrict__ outv) {
    int fl = *flag;
    int y = blockIdx.x, b = blockIdx.y;
    int t = threadIdx.x;
    __shared__ uint32 fb[12672];
    __shared__ ushort vin[16 * 384];
    floatx4 acc[3][8];
#pragma unroll
    for (int ot = 0; ot < 3; ++ot)
#pragma unroll
        for (int nt = 0; nt < 8; ++nt) acc[ot][nt] = (floatx4){0.f, 0.f, 0.f, 0.f};
    proj_branch<1>(0, y, b, t, qkv, dwf, Pbf, fb, vin, acc);
    proj_branch<2>(1, y, b, t, qkv, dwf, Pbf, fb, vin, acc);
    proj_branch<3>(2, y, b, t, qkv, dwf, Pbf, fb, vin, acc);
    // epilogue: o = (w*3+ot)*16 + q*4 + reg, n = y*128 + nt*16 + rr
    int w = t >> 6, lane = t & 63, q = lane >> 4, rr = lane & 15;
#pragma unroll
    for (int ot = 0; ot < 3; ++ot) {
        int o0 = (w * 3 + ot) * 16 + q * 4;
        size_t obase = ((size_t)(b * 192 + o0)) * HW + y * 128 + rr;
        if (fl) {
            float* dst = (float*)outv + obase;
#pragma unroll
            for (int nt = 0; nt < 8; ++nt)
#pragma unroll
                for (int reg = 0; reg < 4; ++reg)
                    dst[(size_t)reg * HW + nt * 16] = acc[ot][nt][reg];
        } else {
            ushort* dst = (ushort*)outv + obase;
#pragma unroll
            for (int nt = 0; nt < 8; ++nt)
#pragma unroll
                for (int reg = 0; reg < 4; ++reg)
                    dst[(size_t)reg * HW + nt * 16] = f2bf(acc[ot][nt][reg]);
        }
    }
}

extern "C" void kernel_launch(void* const* d_in, const int* in_sizes, int n_in,
                              void* d_out, int out_size, void* d_ws, size_t ws_size,
                              hipStream_t stream) {
    const void* x    = d_in[0];
    const void* wqkv = d_in[1];
    const void* dw0  = d_in[2];
    const void* dw1  = d_in[3];
    const void* dw2  = d_in[4];
    const void* wpr  = d_in[5];
    const void* temp = d_in[6];

    char* ws = (char*)d_ws;
    // Layout:
    //   [0, 150994944)           qkv
    //   [150994944, 153550848)   gpart
    //   [153550848, 153772032)   wbf
    //   [153772032, 154214400)   wprojf
    //   [154214400, 154276608)   dwf
    //   [154276608, 154276640)   tempf
    //   [154276640, 154276644)   flag
    //   [154276648, 156046120)   Pbf (1,769,472 B)
    ushort* qkv   = (ushort*)(ws);
    float* gpart  = (float*)(ws + 150994944);
    ushort* wbf   = (ushort*)(ws + 153550848);
    float* wprojf = (float*)(ws + 153772032);
    float* dwf    = (float*)(ws + 154214400);
    float* tempf  = (float*)(ws + 154276608);
    int*   flag   = (int*)(ws + 154276640);
    ushort* Pbf   = (ushort*)(ws + 154276648);

    detect_dtype<<<1, 256, 0, stream>>>((const ushort*)x, flag);
    convert_weights<<<925, 256, 0, stream>>>(wqkv, dw0, dw1, dw2, wpr, temp, flag,
                                             wbf, dwf, wprojf, tempf);
    qkv_mfma<<<1024, 256, 0, stream>>>(x, wbf, flag, qkv);
    gram_fused<1><<<dim3(16, 8, 8), 256, 0, stream>>>(qkv, dwf, gpart, 0);
    attn_p<<<dim3(8, 8), 256, 0, stream>>>(gpart, wprojf, tempf, Pbf, 0);
    gram_fused<2><<<dim3(16, 8, 8), 256, 0, stream>>>(qkv, dwf, gpart, 1);
    attn_p<<<dim3(8, 8), 256, 0, stream>>>(gpart, wprojf, tempf, Pbf, 1);
    gram_fused<3><<<dim3(16, 8, 8), 256, 0, stream>>>(qkv, dwf, gpart, 2);
    attn_p<<<dim3(8, 8), 256, 0, stream>>>(gpart, wprojf, tempf, Pbf, 2);
    proj_mfma<<<dim3(128, 8), 256, 0, stream>>>(qkv, dwf, Pbf, flag, d_out);
}

// Round 5
// 1884.440 us; speedup vs baseline: 1.3183x; 1.0322x over previous
//
#include <hip/hip_runtime.h>

#define HW 16384
typedef unsigned int uint32;
typedef unsigned short ushort;
typedef __attribute__((ext_vector_type(8))) short short8;
typedef __attribute__((ext_vector_type(4))) float floatx4;
typedef __attribute__((ext_vector_type(4))) unsigned int uint32x4;

__device__ __forceinline__ float bf2f(ushort u) {
    union { uint32 i; float f; } x; x.i = ((uint32)u) << 16; return x.f;
}
__device__ __forceinline__ ushort f2bf(float f) {
    union { float f; uint32 i; } x; x.f = f;
    uint32 r = x.i + 0x7fffu + ((x.i >> 16) & 1u);
    return (ushort)(r >> 16);
}

// ---- dtype detector: fp32 data read as bf16 halves has wild exponents ----
__global__ __launch_bounds__(256) void detect_dtype(const ushort* __restrict__ x,
                                                    int* __restrict__ flag) {
    __shared__ int cnt;
    if (threadIdx.x == 0) cnt = 0;
    __syncthreads();
    int c = 0;
    for (int i = threadIdx.x; i < 8192; i += 256) {
        int e = (x[i] >> 7) & 0xFF;
        if (e >= 200) c++;
    }
    atomicAdd(&cnt, c);
    __syncthreads();
    if (threadIdx.x == 0) *flag = (cnt > 100) ? 1 : 0;  // 1 => inputs are fp32
}

// ---- weight convert: wqkv -> bf16 [576][192]; dw,wproj,temp -> fp32 ----
__global__ __launch_bounds__(256) void convert_weights(
    const void* __restrict__ wqkv, const void* __restrict__ dw0,
    const void* __restrict__ dw1, const void* __restrict__ dw2,
    const void* __restrict__ wproj, const void* __restrict__ temp,
    const int* __restrict__ flag,
    ushort* __restrict__ wbf, float* __restrict__ dwf,
    float* __restrict__ wprojf, float* __restrict__ tempf) {
    int fl = *flag;
    int idx = blockIdx.x * 256 + threadIdx.x;
#define RD(p, k) (fl ? ((const float*)(p))[k] : bf2f(((const ushort*)(p))[k]))
    if (idx < 110592) {           // w_qkv [576][192] row-major bf16 (k-contiguous)
        wbf[idx] = f2bf(RD(wqkv, idx));
        return;
    }
    idx -= 110592;
    if (idx < 15552) {            // 3 x [576*9]
        const void* p = (idx < 5184) ? dw0 : ((idx < 10368) ? dw1 : dw2);
        dwf[idx] = RD(p, idx % 5184);
        return;
    }
    idx -= 15552;
    if (idx < 110592) {           // w_proj [192][576] row-major fp32
        wprojf[idx] = RD(wproj, idx);
        return;
    }
    idx -= 110592;
    if (idx < 8) tempf[idx] = RD(temp, idx);
#undef RD
}

// ---- qkv = W @ x via MFMA 16x16x32 bf16. Block: 64 n, all 576 o. ----
// n-split (2048 blocks): bit-identical per output column vs the 128-n version.
__global__ __launch_bounds__(256, 3) void qkv_mfma(const void* __restrict__ xv,
    const ushort* __restrict__ wbf, const int* __restrict__ flag,
    ushort* __restrict__ qkv) {
    int fl = *flag;
    int blk = blockIdx.x;
    int b = blk >> 8; int n0 = (blk & 255) << 6;
    int t = threadIdx.x;
    __shared__ uint32 fb[6336];   // 6 k-steps * 4 n-subtiles * 264 (256 + 8 pad)
    size_t xbase = (size_t)b * 192 * HW + n0;
    for (int k = 0; k < 3; ++k) {
        int seg = t + k * 256;        // 768 segs: 96 c-pairs x 8 n-seg8
        int c2 = seg >> 3;            // 0..95
        int n8 = (seg & 7) << 3;      // 0,8,...,56
        int c = c2 * 2;
        uint32 pk[8];
        if (fl) {
            const float* xp = (const float*)xv + xbase;
            const floatx4* p0 = (const floatx4*)(xp + (size_t)c * HW + n8);
            const floatx4* p1 = (const floatx4*)(xp + (size_t)(c + 1) * HW + n8);
            floatx4 f0a = p0[0], f0b = p0[1];
            floatx4 f1a = p1[0], f1b = p1[1];
#pragma unroll
            for (int i = 0; i < 4; ++i) {
                pk[i]     = (uint32)f2bf(f0a[i]) | ((uint32)f2bf(f1a[i]) << 16);
                pk[i + 4] = (uint32)f2bf(f0b[i]) | ((uint32)f2bf(f1b[i]) << 16);
            }
        } else {
            const ushort* xp = (const ushort*)xv + xbase;
            uint32x4 u0 = *(const uint32x4*)(xp + (size_t)c * HW + n8);
            uint32x4 u1 = *(const uint32x4*)(xp + (size_t)(c + 1) * HW + n8);
#pragma unroll
            for (int wq = 0; wq < 4; ++wq) {
                pk[2 * wq]     = (u0[wq] & 0xffffu) | (u1[wq] << 16);
                pk[2 * wq + 1] = (u0[wq] >> 16) | (u1[wq] & 0xffff0000u);
            }
        }
        int s = c >> 5, q = (c >> 3) & 3, j2 = c2 & 3;
        int nt = n8 >> 4, rb = n8 & 15;
        uint32* dst = fb + (s * 4 + nt) * 264 + (q * 16 + rb) * 4 + j2;
#pragma unroll
        for (int i = 0; i < 8; ++i) dst[i * 4] = pk[i];
    }
    __syncthreads();
    int w = t >> 6, lane = t & 63, q = lane >> 4, rr = lane & 15;
    for (int oc = 0; oc < 9; ++oc) {
        int o0 = oc * 64 + w * 16;
        const ushort* arow = wbf + (size_t)(o0 + rr) * 192;
        floatx4 acc[4];
#pragma unroll
        for (int nt = 0; nt < 4; ++nt) acc[nt] = (floatx4){0.f, 0.f, 0.f, 0.f};
        for (int s = 0; s < 6; ++s) {
            short8 af = *(const short8*)(arow + 32 * s + 8 * q);
            const uint32* bb = fb + s * 4 * 264 + (q * 16 + rr) * 4;
#pragma unroll
            for (int nt = 0; nt < 4; ++nt) {
                short8 bfr = *(const short8*)(bb + nt * 264);
                acc[nt] = __builtin_amdgcn_mfma_f32_16x16x32_bf16(af, bfr, acc[nt], 0, 0, 0);
            }
        }
        // C layout: row(=o) = q*4+reg, col(=n) = rr  [m89/m91 verified]
        ushort* drow = qkv + ((size_t)(b * 576 + o0 + q * 4)) * HW + n0 + rr;
#pragma unroll
        for (int nt = 0; nt < 4; ++nt)
#pragma unroll
            for (int reg = 0; reg < 4; ++reg)
                drow[(size_t)reg * HW + nt * 16] = f2bf(acc[nt][reg]);
    }
}

// ---- fused dwconv(q,k) + gram partials; block = (rowgroup, head, batch) ----
// VERBATIM from round-3 passing kernel (sacred guarded scalar-tap conv).
template<int D>
__global__ __launch_bounds__(256) void gram_fused(const ushort* __restrict__ qkv,
    const float* __restrict__ dwf, float* __restrict__ gpart, int br) {
    int rg = blockIdx.x, hd = blockIdx.y, b = blockIdx.z;
    int t = threadIdx.x;
    __shared__ ushort cs[48 * 132];    // conv outputs, row stride 132
    __shared__ ushort vin[48 * 384];   // staged inputs [cl][ky][128]
    float acc[3] = {0.f, 0.f, 0.f};
    for (int yi = 0; yi < 8; ++yi) {
        int y = rg * 8 + yi;
        __syncthreads();   // protect vin (prior conv reads) and cs (prior dot reads)
        // stage: 48 ch x 3 rows x 16 seg8 = 2304 segs, 9 per thread
        for (int it = 0; it < 9; ++it) {
            int seg = t + it * 256;
            int cl = seg / 48;
            int rem = seg - cl * 48;
            int kyr = rem >> 4;
            int px = (rem & 15) << 3;
            int yy = y + D * (kyr - 1);
            if ((unsigned)yy < 128u) {
                int cg = (cl < 24) ? (hd * 24 + cl) : (192 + hd * 24 + (cl - 24));
                const ushort* src = qkv + ((size_t)(b * 576 + cg)) * HW + (size_t)yy * 128 + px;
                *(short8*)(vin + (cl * 3 + kyr) * 128 + px) = *(const short8*)src;
            }
        }
        __syncthreads();
        // conv compute (LDS source): 6144 outputs, 24 per thread
        for (int it = 0; it < 24; ++it) {
            int e = t + it * 256;
            int cl = e >> 7, xx = e & 127;
            int cg = (cl < 24) ? (hd * 24 + cl) : (192 + hd * 24 + (cl - 24));
            const ushort* vrow = vin + cl * 384;
            const float* w = dwf + (br * 576 + cg) * 9;
            float a = 0.f;
#pragma unroll
            for (int ky = 0; ky < 3; ++ky) {
                int yy = y + D * (ky - 1);
                if ((unsigned)yy < 128u) {
#pragma unroll
                    for (int kx = 0; kx < 3; ++kx) {
                        int x2 = xx + D * (kx - 1);
                        if ((unsigned)x2 < 128u)
                            a = fmaf(bf2f(vrow[ky * 128 + x2]), w[ky * 3 + kx], a);
                    }
                }
            }
            cs[cl * 132 + xx] = f2bf(a);
        }
        __syncthreads();
        const uint32* cs32 = (const uint32*)cs;
#pragma unroll
        for (int pi = 0; pi < 3; ++pi) {
            int p = t + pi * 256;
            if (p >= 624) break;
            int i, j;
            if (p < 576)      { i = p / 24;         j = 24 + p % 24; }
            else if (p < 600) { i = p - 576;        j = i; }
            else              { i = 24 + (p - 600); j = i; }
            const uint32* ra = cs32 + i * 66;
            const uint32* rb = cs32 + j * 66;
            float s = acc[pi];
            for (int xi = 0; xi < 64; ++xi) {
                uint32 ua = ra[xi], ub = rb[xi];
                s = fmaf(bf2f((ushort)(ua & 0xffff)), bf2f((ushort)(ub & 0xffff)), s);
                s = fmaf(bf2f((ushort)(ua >> 16)), bf2f((ushort)(ub >> 16)), s);
            }
            acc[pi] = s;
        }
    }
    float* gp = gpart + ((size_t)((b * 8 + hd) * 16 + rg)) * 624;
#pragma unroll
    for (int pi = 0; pi < 3; ++pi) {
        int p = t + pi * 256;
        if (p < 624) gp[p] = acc[pi];
    }
}

// ---- reduce gram, softmax, fold with w_proj -> Pbf[br][o][c] bf16 ----
__global__ __launch_bounds__(256) void attn_p(const float* __restrict__ gpart,
    const float* __restrict__ wprojf, const float* __restrict__ tempf,
    ushort* __restrict__ Pbf, int br) {
    int otile = blockIdx.x; int b_ = blockIdx.y;
    int t = threadIdx.x;
    __shared__ float G[8][624];
    __shared__ float A[8][24][24];
    for (int e = t; e < 8 * 624; e += 256) {
        int hd = e / 624, idx = e % 624;
        const float* gp = gpart + ((size_t)((b_ * 8 + hd) * 16)) * 624 + idx;
        float s = 0.f;
#pragma unroll
        for (int rgi = 0; rgi < 16; ++rgi) s += gp[(size_t)rgi * 624];
        G[hd][idx] = s;
    }
    __syncthreads();
    if (t < 192) {
        int hd = t / 24, i = t % 24;
        const float* g = G[hd];
        float dq = fmaxf(sqrtf(fmaxf(g[576 + i], 0.f)), 1e-12f);
        float tv = tempf[hd];
        float lg[24]; float mx = -1e30f;
#pragma unroll
        for (int j = 0; j < 24; ++j) {
            float kn = fmaxf(sqrtf(fmaxf(g[600 + j], 0.f)), 1e-12f);
            lg[j] = g[i * 24 + j] / (dq * kn) * tv;
            mx = fmaxf(mx, lg[j]);
        }
        float sum = 0.f;
#pragma unroll
        for (int j = 0; j < 24; ++j) { lg[j] = __expf(lg[j] - mx); sum += lg[j]; }
        float inv = 1.f / sum;
#pragma unroll
        for (int j = 0; j < 24; ++j) A[hd][i][j] = lg[j] * inv;
    }
    __syncthreads();
    for (int e = t; e < 24 * 192; e += 256) {
        int o = otile * 24 + (e % 24);
        int c = e / 24;
        int hd = c / 24, dd = c % 24;
        const float* wr = wprojf + o * 576 + br * 192 + hd * 24;
        float s = 0.f;
#pragma unroll
        for (int i = 0; i < 24; ++i) s = fmaf(wr[i], A[hd][i][dd], s);
        Pbf[((size_t)(b_ * 3 + br) * 192 + o) * 192 + c] = f2bf(s);
    }
}

// ---- fused conv(v) + MFMA proj; n-split to 64-px tiles (bit-exact columns) ----
template<int D>
__device__ __forceinline__ void proj_branch(int br, int y, int b, int t, int n0, int w0,
    const ushort* __restrict__ qkv, const float* __restrict__ dwf,
    const ushort* __restrict__ Pbf, uint32* fb, ushort* vin, floatx4 (&acc)[3][4]) {
    ushort* fbs = (ushort*)fb;
    const ushort* qv = qkv + ((size_t)(b * 576 + 384)) * HW;
    const float* dwb = dwf + (br * 576 + 384) * 9;
    for (int cc = 0; cc < 12; ++cc) {   // 12 chunks x 16 channels
        __syncthreads();                // protects vin reuse and fb (prior MFMA reads)
        // stage 80-px windows: 16 ch x 3 rows x 10 seg8 = 480 segs
        for (int k = 0; k < 2; ++k) {
            int seg = t + k * 256;
            if (seg < 480) {
                int chl = seg / 30;
                int rem = seg - chl * 30;
                int kyr = rem / 10;
                int sxl = (rem - kyr * 10) << 3;
                int yy = y + D * (kyr - 1);
                if ((unsigned)yy < 128u) {
                    int c = cc * 16 + chl;
                    const ushort* src = qv + (size_t)c * HW + (size_t)yy * 128 + w0 + sxl;
                    *(short8*)(vin + (chl * 3 + kyr) * 80 + sxl) = *(const short8*)src;
                }
            }
        }
        __syncthreads();
        // conv compute (guarded scalar taps, LDS source): 1024 outputs, 4/thread
        for (int k = 0; k < 4; ++k) {
            int e = t + k * 256;
            int chl = e >> 6, xxl = e & 63;
            int xx = n0 + xxl;
            int c = cc * 16 + chl;
            const ushort* vrow = vin + chl * 240;
            const float* wv = dwb + c * 9;
            float a = 0.f;
#pragma unroll
            for (int ky = 0; ky < 3; ++ky) {
                int yy = y + D * (ky - 1);
                if ((unsigned)yy < 128u) {
#pragma unroll
                    for (int kx = 0; kx < 3; ++kx) {
                        int x2 = xx + D * (kx - 1);
                        if ((unsigned)x2 < 128u)
                            a = fmaf(bf2f(vrow[ky * 80 + x2 - w0]), wv[ky * 3 + kx], a);
                    }
                }
            }
            int s = c >> 5, qq = (c >> 3) & 3, j = c & 7;
            int nt = xxl >> 4, r = xxl & 15;
            fbs[((s * 4 + nt) * 264 + (qq * 16 + r) * 4) * 2 + j] = f2bf(a);
        }
    }
    __syncthreads();
    int w = t >> 6, lane = t & 63, q = lane >> 4, rr = lane & 15;
    const ushort* Pb = Pbf + ((size_t)(b * 3 + br) * 192) * 192;
    for (int s = 0; s < 6; ++s) {
        short8 bfr[4];
        const uint32* bb = fb + s * 4 * 264 + (q * 16 + rr) * 4;
#pragma unroll
        for (int nt = 0; nt < 4; ++nt) bfr[nt] = *(const short8*)(bb + nt * 264);
#pragma unroll
        for (int ot = 0; ot < 3; ++ot) {
            int o0 = (w * 3 + ot) * 16;
            short8 af = *(const short8*)(Pb + (size_t)(o0 + rr) * 192 + 32 * s + 8 * q);
#pragma unroll
            for (int nt = 0; nt < 4; ++nt)
                acc[ot][nt] = __builtin_amdgcn_mfma_f32_16x16x32_bf16(af, bfr[nt], acc[ot][nt], 0, 0, 0);
        }
    }
}

__global__ __launch_bounds__(256, 2) void proj_mfma(const ushort* __restrict__ qkv,
    const float* __restrict__ dwf, const ushort* __restrict__ Pbf,
    const int* __restrict__ flag, void* __restrict__ outv) {
    int fl = *flag;
    int y = blockIdx.x >> 1;
    int n0 = (blockIdx.x & 1) << 6;
    int w0 = (n0 == 0) ? 0 : n0 - 8;
    int b = blockIdx.y;
    int t = threadIdx.x;
    __shared__ uint32 fb[6336];
    __shared__ ushort vin[16 * 240];
    floatx4 acc[3][4];
#pragma unroll
    for (int ot = 0; ot < 3; ++ot)
#pragma unroll
        for (int nt = 0; nt < 4; ++nt) acc[ot][nt] = (floatx4){0.f, 0.f, 0.f, 0.f};
    proj_branch<1>(0, y, b, t, n0, w0, qkv, dwf, Pbf, fb, vin, acc);
    proj_branch<2>(1, y, b, t, n0, w0, qkv, dwf, Pbf, fb, vin, acc);
    proj_branch<3>(2, y, b, t, n0, w0, qkv, dwf, Pbf, fb, vin, acc);
    // epilogue: o = (w*3+ot)*16 + q*4 + reg, n = y*128 + n0 + nt*16 + rr
    int w = t >> 6, lane = t & 63, q = lane >> 4, rr = lane & 15;
#pragma unroll
    for (int ot = 0; ot < 3; ++ot) {
        int o0 = (w * 3 + ot) * 16 + q * 4;
        size_t obase = ((size_t)(b * 192 + o0)) * HW + y * 128 + n0 + rr;
        if (fl) {
            float* dst = (float*)outv + obase;
#pragma unroll
            for (int nt = 0; nt < 4; ++nt)
#pragma unroll
                for (int reg = 0; reg < 4; ++reg)
                    dst[(size_t)reg * HW + nt * 16] = acc[ot][nt][reg];
        } else {
            ushort* dst = (ushort*)outv + obase;
#pragma unroll
            for (int nt = 0; nt < 4; ++nt)
#pragma unroll
                for (int reg = 0; reg < 4; ++reg)
                    dst[(size_t)reg * HW + nt * 16] = f2bf(acc[ot][nt][reg]);
        }
    }
}

extern "C" void kernel_launch(void* const* d_in, const int* in_sizes, int n_in,
                              void* d_out, int out_size, void* d_ws, size_t ws_size,
                              hipStream_t stream) {
    const void* x    = d_in[0];
    const void* wqkv = d_in[1];
    const void* dw0  = d_in[2];
    const void* dw1  = d_in[3];
    const void* dw2  = d_in[4];
    const void* wpr  = d_in[5];
    const void* temp = d_in[6];

    char* ws = (char*)d_ws;
    // Layout:
    //   [0, 150994944)           qkv
    //   [150994944, 153550848)   gpart
    //   [153550848, 153772032)   wbf
    //   [153772032, 154214400)   wprojf
    //   [154214400, 154276608)   dwf
    //   [154276608, 154276640)   tempf
    //   [154276640, 154276644)   flag
    //   [154276648, 156046120)   Pbf (1,769,472 B)
    ushort* qkv   = (ushort*)(ws);
    float* gpart  = (float*)(ws + 150994944);
    ushort* wbf   = (ushort*)(ws + 153550848);
    float* wprojf = (float*)(ws + 153772032);
    float* dwf    = (float*)(ws + 154214400);
    float* tempf  = (float*)(ws + 154276608);
    int*   flag   = (int*)(ws + 154276640);
    ushort* Pbf   = (ushort*)(ws + 154276648);

    detect_dtype<<<1, 256, 0, stream>>>((const ushort*)x, flag);
    convert_weights<<<925, 256, 0, stream>>>(wqkv, dw0, dw1, dw2, wpr, temp, flag,
                                             wbf, dwf, wprojf, tempf);
    qkv_mfma<<<2048, 256, 0, stream>>>(x, wbf, flag, qkv);
    gram_fused<1><<<dim3(16, 8, 8), 256, 0, stream>>>(qkv, dwf, gpart, 0);
    attn_p<<<dim3(8, 8), 256, 0, stream>>>(gpart, wprojf, tempf, Pbf, 0);
    gram_fused<2><<<dim3(16, 8, 8), 256, 0, stream>>>(qkv, dwf, gpart, 1);
    attn_p<<<dim3(8, 8), 256, 0, stream>>>(gpart, wprojf, tempf, Pbf, 1);
    gram_fused<3><<<dim3(16, 8, 8), 256, 0, stream>>>(qkv, dwf, gpart, 2);
    attn_p<<<dim3(8, 8), 256, 0, stream>>>(gpart, wprojf, tempf, Pbf, 2);
    proj_mfma<<<dim3(256, 8), 256, 0, stream>>>(qkv, dwf, Pbf, flag, d_out);
}